// Round 2
// baseline (3029.940 us; speedup 1.0000x reference)
//
#include <hip/hip_runtime.h>

// simpleKT forward on gfx950: bf16 MFMA GEMMs + flash-style causal attention.
// B=64 S=512 D=512 H=8 DK=64 L=4 DFF=2048 NSK=300 FC1=512 FC2=256.
// Workspace-adaptive: batch-group chunking (NC in {1,4,8}) keyed off ws_size.

typedef unsigned short u16;
typedef __attribute__((ext_vector_type(8))) short short8;   // 8 bf16 (4 VGPRs) - MFMA A/B frag
typedef __attribute__((ext_vector_type(4))) float f32x4;    // MFMA C/D frag

#define DEV __device__ __forceinline__

DEV float bf2f(u16 u) { return __uint_as_float(((unsigned int)u) << 16); }
DEV u16 f2bf(float f) {
  unsigned int u = __float_as_uint(f);
  u += 0x7FFFu + ((u >> 16) & 1u);
  return (u16)(u >> 16);
}

DEV void gl2l16(const void* g, void* l) {
  // async global->LDS, 16B per lane; LDS dest = wave-uniform base + lane*16
  __builtin_amdgcn_global_load_lds(
      (__attribute__((address_space(1))) void*)g,
      (__attribute__((address_space(3))) void*)l, 16, 0, 0);
}

#define MFMA16(a, b, c) __builtin_amdgcn_mfma_f32_16x16x32_bf16(a, b, c, 0, 0, 0)

// ---------------------------------------------------------------------------
// Weight convert+transpose: fp32 [K,N] (batched over z) -> bf16 [N,K]
// ---------------------------------------------------------------------------
__global__ __launch_bounds__(256) void transpose_cvt(
    const float* __restrict__ src, u16* __restrict__ dst, int K, int N)
{
  src += (size_t)blockIdx.z * K * N;
  dst += (size_t)blockIdx.z * K * N;
  __shared__ alignas(16) float tile[32][33];
  const int tx = threadIdx.x & 31, ty = threadIdx.x >> 5;
  const int n0 = blockIdx.x * 32, k0 = blockIdx.y * 32;
#pragma unroll
  for (int i = 0; i < 4; ++i) {
    int k = k0 + ty + i * 8, n = n0 + tx;
    if (k < K && n < N) tile[ty + i * 8][tx] = src[(size_t)k * N + n];
  }
  __syncthreads();
#pragma unroll
  for (int i = 0; i < 4; ++i) {
    int n = n0 + ty + i * 8, k = k0 + tx;
    if (n < N && k < K) dst[(size_t)n * K + k] = f2bf(tile[tx][ty + i * 8]);
  }
}

// ---------------------------------------------------------------------------
// Embedding: x = q_emb[q_data] + pe[s]; y = qa_emb[target] + q_emb[q_data] + pe[s]
// one wave per row (512 cols, 8/lane)
// ---------------------------------------------------------------------------
__global__ __launch_bounds__(256) void embed_k(
    const int* __restrict__ qd, const int* __restrict__ tg,
    const float* __restrict__ pe, const float* __restrict__ qe, const float* __restrict__ qa,
    u16* __restrict__ x_b, u16* __restrict__ y_b)
{
  const int row = blockIdx.x * 4 + (threadIdx.x >> 6);
  const int lane = threadIdx.x & 63;
  const int s = row & 511;
  const int idx = qd[row];
  const int tt = tg[row];
  const int c = lane * 8;
  const float* q = qe + (size_t)idx * 512 + c;
  const float* p = pe + (size_t)s * 512 + c;
  const float* a = qa + (size_t)tt * 512 + c;
  float4 q0 = *(const float4*)q, q1 = *(const float4*)(q + 4);
  float4 p0 = *(const float4*)p, p1 = *(const float4*)(p + 4);
  float4 a0 = *(const float4*)a, a1 = *(const float4*)(a + 4);
  float qv[8] = {q0.x, q0.y, q0.z, q0.w, q1.x, q1.y, q1.z, q1.w};
  float pv[8] = {p0.x, p0.y, p0.z, p0.w, p1.x, p1.y, p1.z, p1.w};
  float av[8] = {a0.x, a0.y, a0.z, a0.w, a1.x, a1.y, a1.z, a1.w};
  short8 ox, oy;
#pragma unroll
  for (int i = 0; i < 8; ++i) {
    ox[i] = (short)f2bf(qv[i] + pv[i]);
    oy[i] = (short)f2bf(qv[i] + pv[i] + av[i]);
  }
  size_t base = (size_t)row * 512 + c;
  *(short8*)(x_b + base) = ox;
  *(short8*)(y_b + base) = oy;
}

// ---------------------------------------------------------------------------
// bf16 GEMM (m97 structure): C[M,N] = act(A[M,K] @ Bt[N,K]^T + bias)
// 128x128 tile, BK=32, 256 thr (2x2 waves, each 64x64 = 4x4 16x16x32 MFMA).
// XOR chunk swizzle keeps LDS bank conflicts <=2-way and global_load_lds-compatible.
// OUTM: 0 = bf16 row-major, 1 = f32 row-major, 2 = bf16 scatter into vT[b,h,dk,s]
// ---------------------------------------------------------------------------
template <int ACT, int OUTM>
__global__ __launch_bounds__(256) void gemm_bt(
    const u16* __restrict__ A, const u16* __restrict__ Bt,
    const float* __restrict__ bias, void* __restrict__ Cv,
    int M, int N, int K)
{
  __shared__ alignas(16) u16 As[128 * 32];
  __shared__ alignas(16) u16 Bs[128 * 32];
  const int lane = threadIdx.x & 63;
  const int w = threadIdx.x >> 6;
  const int wm = w >> 1, wn = w & 1;
  const int m0 = blockIdx.y * 128, n0 = blockIdx.x * 128;

  const u16* pa[2];
  const u16* pb[2];
  u16* la[2];
  u16* lb[2];
#pragma unroll
  for (int i = 0; i < 2; ++i) {
    int tb = w * 2 + i;
    int r = tb * 16 + (lane >> 2);
    int ps = (lane & 3) ^ ((r >> 1) & 3);
    pa[i] = A + (size_t)(m0 + r) * K + ps * 8;
    int rb = n0 + r;
    rb = (rb < N) ? rb : (N - 1);
    pb[i] = Bt + (size_t)rb * K + ps * 8;
    la[i] = As + (tb * 64 + lane) * 8;
    lb[i] = Bs + (tb * 64 + lane) * 8;
  }
  const u16* ra[4];
  const u16* rbp[4];
#pragma unroll
  for (int i = 0; i < 4; ++i) {
    int r = wm * 64 + i * 16 + (lane & 15);
    ra[i] = As + (r * 4 + ((lane >> 4) ^ ((r >> 1) & 3))) * 8;
    int r2 = wn * 64 + i * 16 + (lane & 15);
    rbp[i] = Bs + (r2 * 4 + ((lane >> 4) ^ ((r2 >> 1) & 3))) * 8;
  }

  f32x4 acc[4][4];
#pragma unroll
  for (int a_ = 0; a_ < 4; ++a_)
#pragma unroll
    for (int b_ = 0; b_ < 4; ++b_)
#pragma unroll
      for (int i = 0; i < 4; ++i) acc[a_][b_][i] = 0.f;

  for (int k0 = 0; k0 < K; k0 += 32) {
    gl2l16(pa[0], la[0]);
    gl2l16(pa[1], la[1]);
    gl2l16(pb[0], lb[0]);
    gl2l16(pb[1], lb[1]);
    pa[0] += 32; pa[1] += 32; pb[0] += 32; pb[1] += 32;
    __syncthreads();
    short8 af[4], bf[4];
#pragma unroll
    for (int i = 0; i < 4; ++i) af[i] = *(const short8*)ra[i];
#pragma unroll
    for (int i = 0; i < 4; ++i) bf[i] = *(const short8*)rbp[i];
#pragma unroll
    for (int mt = 0; mt < 4; ++mt)
#pragma unroll
      for (int nt = 0; nt < 4; ++nt)
        acc[mt][nt] = MFMA16(af[mt], bf[nt], acc[mt][nt]);
    __syncthreads();
  }

  const int row0 = m0 + wm * 64, col0 = n0 + wn * 64;
#pragma unroll
  for (int mt = 0; mt < 4; ++mt) {
#pragma unroll
    for (int nt = 0; nt < 4; ++nt) {
      int c = col0 + nt * 16 + (lane & 15);
      int r = row0 + mt * 16 + (lane >> 4) * 4;
      if (c < N) {
        float bz = bias[c];
#pragma unroll
        for (int i = 0; i < 4; ++i) {
          float v = acc[mt][nt][i] + bz;
          if (ACT == 1) v = fmaxf(v, 0.f);
          int m = r + i;
          if (OUTM == 0) {
            ((u16*)Cv)[(size_t)m * N + c] = f2bf(v);
          } else if (OUTM == 1) {
            ((float*)Cv)[(size_t)m * N + c] = v;
          } else {  // vT[b][h][dk][s]: m=(b,s) local, c=(h,dk)
            size_t idx = ((((size_t)(m >> 9)) * 8 + (c >> 6)) * 64 + (c & 63)) * 512 + (m & 511);
            ((u16*)Cv)[idx] = f2bf(v);
          }
        }
      }
    }
  }
}

// ---------------------------------------------------------------------------
// Flash-style causal attention. grid (qtile=4, h=8, b=NB), 256 thr = 4 waves.
// Per block: Q tile [128,64]; iterate key chunks [128], strict causal (j<i),
// online softmax; row 0 zeroed. LDS = 16K(Ks)+16K(Vs)+32K(Ps) = 64KB.
// ---------------------------------------------------------------------------
__global__ __launch_bounds__(256) void attn_k(
    const u16* __restrict__ kq, const u16* __restrict__ vT, u16* __restrict__ o)
{
  __shared__ alignas(16) u16 Ks[128 * 64];
  __shared__ alignas(16) u16 Vs[64 * 128];
  __shared__ alignas(16) u16 Ps[128 * 128];
  const int t = blockIdx.x, h = blockIdx.y, b = blockIdx.z;
  const int lane = threadIdx.x & 63;
  const int w = threadIdx.x >> 6;
  const int q0 = t * 128;
  const size_t kq_base = ((size_t)b * 512) * 512 + h * 64;

  // stage Q tile into Ps region (first 8192 u16), swizzled rows of 8 chunks
#pragma unroll
  for (int i = 0; i < 4; ++i) {
    int tb = w * 4 + i;
    int r = tb * 8 + (lane >> 3);
    int ps = (lane & 7) ^ (r & 7);
    gl2l16(kq + kq_base + (size_t)(q0 + r) * 512 + ps * 8, Ps + (tb * 64 + lane) * 8);
  }
  __syncthreads();
  short8 qf[2][2];
#pragma unroll
  for (int mt = 0; mt < 2; ++mt)
#pragma unroll
    for (int ks = 0; ks < 2; ++ks) {
      int q = w * 32 + mt * 16 + (lane & 15);
      int ch = ks * 4 + (lane >> 4);
      qf[mt][ks] = *(const short8*)(Ps + (q * 8 + (ch ^ (q & 7))) * 8);
    }

  f32x4 of[2][4];
  float m_st[2][4], l_st[2][4];
#pragma unroll
  for (int mt = 0; mt < 2; ++mt)
#pragma unroll
    for (int i = 0; i < 4; ++i) {
      m_st[mt][i] = -1e30f;
      l_st[mt][i] = 0.f;
#pragma unroll
      for (int nd = 0; nd < 4; ++nd) of[mt][nd][i] = 0.f;
    }

  for (int j = 0; j <= t; ++j) {
    const int k0 = j * 128;
    __syncthreads();  // prior-iteration LDS reads (and qf reads) drained before restage
#pragma unroll
    for (int i = 0; i < 4; ++i) {  // K chunk [128 keys x 64]
      int tb = w * 4 + i;
      int r = tb * 8 + (lane >> 3);
      int ps = (lane & 7) ^ (r & 7);
      gl2l16(kq + kq_base + (size_t)(k0 + r) * 512 + ps * 8, Ks + (tb * 64 + lane) * 8);
    }
#pragma unroll
    for (int i = 0; i < 4; ++i) {  // V^T chunk [64 dk x 128 keys]
      int tb = w * 4 + i;
      int r = tb * 4 + (lane >> 4);
      int ps = (lane & 15) ^ (r & 15);
      gl2l16(vT + ((size_t)((b * 8 + h) * 64 + r)) * 512 + k0 + ps * 8, Vs + (tb * 64 + lane) * 8);
    }
    __syncthreads();

    // scores = Q K^T : wave covers 32 q-rows x 128 keys
    f32x4 sc[2][8];
#pragma unroll
    for (int mt = 0; mt < 2; ++mt)
#pragma unroll
      for (int nt = 0; nt < 8; ++nt)
#pragma unroll
        for (int i = 0; i < 4; ++i) sc[mt][nt][i] = 0.f;
#pragma unroll
    for (int nt = 0; nt < 8; ++nt) {
#pragma unroll
      for (int ks = 0; ks < 2; ++ks) {
        int n = nt * 16 + (lane & 15);
        int ch = ks * 4 + (lane >> 4);
        short8 kf = *(const short8*)(Ks + (n * 8 + (ch ^ (n & 7))) * 8);
        sc[0][nt] = MFMA16(qf[0][ks], kf, sc[0][nt]);
        sc[1][nt] = MFMA16(qf[1][ks], kf, sc[1][nt]);
      }
    }

    // scale + strict causal mask (diagonal chunk only)
#pragma unroll
    for (int mt = 0; mt < 2; ++mt) {
      int qg = q0 + w * 32 + mt * 16 + (lane >> 4) * 4;
#pragma unroll
      for (int nt = 0; nt < 8; ++nt) {
        int kg = k0 + nt * 16 + (lane & 15);
#pragma unroll
        for (int i = 0; i < 4; ++i) {
          float v = sc[mt][nt][i] * 0.125f;
          if (j == t && kg >= qg + i) v = -1e30f;
          sc[mt][nt][i] = v;
        }
      }
    }

    // online softmax (rows live in 16-lane groups; reg i <-> row (lane>>4)*4+i)
#pragma unroll
    for (int mt = 0; mt < 2; ++mt)
#pragma unroll
      for (int i = 0; i < 4; ++i) {
        float mx = sc[mt][0][i];
#pragma unroll
        for (int nt = 1; nt < 8; ++nt) mx = fmaxf(mx, sc[mt][nt][i]);
#pragma unroll
        for (int d = 1; d < 16; d <<= 1) mx = fmaxf(mx, __shfl_xor(mx, d));
        float mo = m_st[mt][i];
        float mn = fmaxf(mo, mx);
        float al = __expf(mo - mn);
        float rs = 0.f;
#pragma unroll
        for (int nt = 0; nt < 8; ++nt) {
          float pv = __expf(sc[mt][nt][i] - mn);
          sc[mt][nt][i] = pv;
          rs += pv;
        }
#pragma unroll
        for (int d = 1; d < 16; d <<= 1) rs += __shfl_xor(rs, d);
        m_st[mt][i] = mn;
        l_st[mt][i] = l_st[mt][i] * al + rs;
#pragma unroll
        for (int nd = 0; nd < 4; ++nd) of[mt][nd][i] *= al;
      }

    // P (C-layout) -> Ps row-major [q][k], chunk-swizzled for A-frag reads
#pragma unroll
    for (int mt = 0; mt < 2; ++mt)
#pragma unroll
      for (int nt = 0; nt < 8; ++nt) {
        int k = nt * 16 + (lane & 15);
#pragma unroll
        for (int i = 0; i < 4; ++i) {
          int q = w * 32 + mt * 16 + (lane >> 4) * 4 + i;
          Ps[(q * 16 + ((k >> 3) ^ (q & 15))) * 8 + (k & 7)] = f2bf(sc[mt][nt][i]);
        }
      }
    __syncthreads();

    // O += P V : A-frags from Ps, B-frags from Vs
#pragma unroll
    for (int ks = 0; ks < 4; ++ks) {
      short8 pf[2];
#pragma unroll
      for (int mt = 0; mt < 2; ++mt) {
        int q = w * 32 + mt * 16 + (lane & 15);
        int ch = ks * 4 + (lane >> 4);
        pf[mt] = *(const short8*)(Ps + (q * 16 + (ch ^ (q & 15))) * 8);
      }
#pragma unroll
      for (int nd = 0; nd < 4; ++nd) {
        int dk = nd * 16 + (lane & 15);
        int ch = ks * 4 + (lane >> 4);
        short8 vf = *(const short8*)(Vs + (dk * 16 + (ch ^ (dk & 15))) * 8);
        of[0][nd] = MFMA16(pf[0], vf, of[0][nd]);
        of[1][nd] = MFMA16(pf[1], vf, of[1][nd]);
      }
    }
  }

  // O / l, row 0 forced to zero; write o[b,s, h*64+dk]
#pragma unroll
  for (int mt = 0; mt < 2; ++mt)
#pragma unroll
    for (int i = 0; i < 4; ++i) {
      int qg = q0 + w * 32 + mt * 16 + (lane >> 4) * 4 + i;
      float li = l_st[mt][i];
      float inv = (qg > 0 && li > 0.f) ? (1.f / li) : 0.f;
#pragma unroll
      for (int nd = 0; nd < 4; ++nd) {
        int dk = nd * 16 + (lane & 15);
        o[((size_t)b * 512 + qg) * 512 + h * 64 + dk] = f2bf(of[mt][nd][i] * inv);
      }
    }
}

// ---------------------------------------------------------------------------
// LayerNorm(x + res) with gamma/beta; one wave per 512-col row; in-place safe.
// ---------------------------------------------------------------------------
__global__ __launch_bounds__(256) void ln_res(
    const u16* __restrict__ xin, const u16* __restrict__ res,
    const float* __restrict__ gam, const float* __restrict__ bet, u16* __restrict__ xout)
{
  const int row = blockIdx.x * 4 + (threadIdx.x >> 6);
  const int lane = threadIdx.x & 63;
  const size_t base = (size_t)row * 512 + lane * 8;
  short8 xv = *(const short8*)(xin + base);
  short8 rv = *(const short8*)(res + base);
  float v[8];
  float s = 0.f, s2 = 0.f;
#pragma unroll
  for (int i = 0; i < 8; ++i) {
    float a = bf2f((u16)xv[i]) + bf2f((u16)rv[i]);
    v[i] = a;
    s += a;
    s2 += a * a;
  }
#pragma unroll
  for (int d = 1; d < 64; d <<= 1) {
    s += __shfl_xor(s, d);
    s2 += __shfl_xor(s2, d);
  }
  float mean = s * (1.f / 512.f);
  float var = s2 * (1.f / 512.f) - mean * mean;
  float rstd = rsqrtf(var + 1e-5f);
  const int c = lane * 8;
  short8 ov;
#pragma unroll
  for (int i = 0; i < 8; ++i) {
    float o = (v[i] - mean) * rstd * gam[c + i] + bet[c + i];
    ov[i] = (short)f2bf(o);
  }
  *(short8*)(xout + base) = ov;
}

// ---------------------------------------------------------------------------
// concat [x, q_emb[q_data]] -> cat [rows,1024] bf16 (qe re-gathered from fp32)
// ---------------------------------------------------------------------------
__global__ __launch_bounds__(256) void concat2_k(
    const u16* __restrict__ x, const int* __restrict__ qd,
    const float* __restrict__ qemb, u16* __restrict__ cat)
{
  const int row = blockIdx.x * 4 + (threadIdx.x >> 6);
  const int lane = threadIdx.x & 63;
  *(short8*)(cat + (size_t)row * 1024 + lane * 8) =
      *(const short8*)(x + (size_t)row * 512 + lane * 8);
  const int idx = qd[row];
  const float* q = qemb + (size_t)idx * 512 + lane * 8;
  float4 q0 = *(const float4*)q, q1 = *(const float4*)(q + 4);
  float qv[8] = {q0.x, q0.y, q0.z, q0.w, q1.x, q1.y, q1.z, q1.w};
  short8 o;
#pragma unroll
  for (int i = 0; i < 8; ++i) o[i] = (short)f2bf(qv[i]);
  *(short8*)(cat + (size_t)row * 1024 + 512 + lane * 8) = o;
}

// ---------------------------------------------------------------------------
extern "C" void kernel_launch(void* const* d_in, const int* in_sizes, int n_in,
                              void* d_out, int out_size, void* d_ws, size_t ws_size,
                              hipStream_t stream)
{
  const int* qd = (const int*)d_in[0];
  const int* tg = (const int*)d_in[1];
  const float* pe = (const float*)d_in[2];
  const float* qemb = (const float*)d_in[3];
  const float* qa = (const float*)d_in[4];
  const float* Wk = (const float*)d_in[5];
  const float* bk = (const float*)d_in[6];
  const float* Wv = (const float*)d_in[7];
  const float* bv = (const float*)d_in[8];
  const float* Wo = (const float*)d_in[9];
  const float* bo = (const float*)d_in[10];
  const float* g1 = (const float*)d_in[11];
  const float* be1 = (const float*)d_in[12];
  const float* W1 = (const float*)d_in[13];
  const float* b1 = (const float*)d_in[14];
  const float* W2 = (const float*)d_in[15];
  const float* b2 = (const float*)d_in[16];
  const float* g2 = (const float*)d_in[17];
  const float* be2 = (const float*)d_in[18];
  const float* Wo1 = (const float*)d_in[19];
  const float* bo1 = (const float*)d_in[20];
  const float* Wo2 = (const float*)d_in[21];
  const float* bo2 = (const float*)d_in[22];
  const float* Wo3 = (const float*)d_in[23];
  const float* bo3 = (const float*)d_in[24];
  float* out = (float*)d_out;

  const int BS = 64 * 512;  // 32768

  // pick batch-group chunking from ws_size (constant per process -> graph-safe)
  const size_t WU16 = 12266496ull;  // all bf16 weights
  int NC = 1;
  {
    auto need = [&](int nc) -> size_t {
      size_t CMr = (size_t)BS / nc;
      size_t st = CMr < 8192 ? CMr : 8192;
      return 2ull * (WU16 + 2ull * BS * 512 + 3ull * CMr * 512 + st * 2048);
    };
    if (ws_size < need(1)) NC = 4;
    if (NC == 4 && ws_size < need(4)) NC = 8;
  }
  const int CM = BS / NC;                 // rows per chunk (multiple of 512)
  const int MI = CM < 8192 ? CM : 8192;   // FFN inner chunk rows

  u16* p = (u16*)d_ws;
  u16* wkT = p;  p += 4 * 512 * 512;
  u16* wvT = p;  p += 4 * 512 * 512;
  u16* woT = p;  p += 4 * 512 * 512;
  u16* w1T = p;  p += 4 * 512 * 2048;
  u16* w2T = p;  p += 4 * 2048 * 512;
  u16* wo1T = p; p += 1024 * 512;
  u16* wo2T = p; p += 512 * 256;
  u16* wo3T = p; p += 300 * 256;
  u16* x_b = p;  p += (size_t)BS * 512;
  u16* y_b = p;  p += (size_t)BS * 512;
  u16* s_kq = p; p += (size_t)CM * 512;   // also head-cat first half
  u16* s_vT = p; p += (size_t)CM * 512;   // adjacent: cat = s_kq[CM x 1024]
  u16* s_o = p;  p += (size_t)CM * 512;
  u16* s_t = p;                            // MI x 2048 FFN / head scratch

  // weights -> bf16 [out,in]
  transpose_cvt<<<dim3(16, 16, 4), 256, 0, stream>>>(Wk, wkT, 512, 512);
  transpose_cvt<<<dim3(16, 16, 4), 256, 0, stream>>>(Wv, wvT, 512, 512);
  transpose_cvt<<<dim3(16, 16, 4), 256, 0, stream>>>(Wo, woT, 512, 512);
  transpose_cvt<<<dim3(64, 16, 4), 256, 0, stream>>>(W1, w1T, 512, 2048);
  transpose_cvt<<<dim3(16, 64, 4), 256, 0, stream>>>(W2, w2T, 2048, 512);
  transpose_cvt<<<dim3(16, 32, 1), 256, 0, stream>>>(Wo1, wo1T, 1024, 512);
  transpose_cvt<<<dim3(8, 16, 1), 256, 0, stream>>>(Wo2, wo2T, 512, 256);
  transpose_cvt<<<dim3(10, 8, 1), 256, 0, stream>>>(Wo3, wo3T, 256, 300);

  embed_k<<<BS / 4, 256, 0, stream>>>(qd, tg, pe, qemb, qa, x_b, y_b);

  for (int l = 0; l < 4; ++l) {
    const size_t lw = (size_t)l * 512 * 512;
    for (int cc = 0; cc < NC; ++cc) {
      const size_t R = (size_t)cc * CM;
      // q/k projection (kq_same=1: single GEMM)
      gemm_bt<0, 0><<<dim3(4, CM / 128), 256, 0, stream>>>(
          x_b + R * 512, wkT + lw, bk + l * 512, s_kq, CM, 512, 512);
      // v projection, written directly as vT[b_local,h,dk,s]
      gemm_bt<0, 2><<<dim3(4, CM / 128), 256, 0, stream>>>(
          y_b + R * 512, wvT + lw, bv + l * 512, s_vT, CM, 512, 512);
      attn_k<<<dim3(4, 8, CM / 512), 256, 0, stream>>>(s_kq, s_vT, s_o);
      // output projection (reuse s_kq)
      gemm_bt<0, 0><<<dim3(4, CM / 128), 256, 0, stream>>>(
          s_o, woT + lw, bo + l * 512, s_kq, CM, 512, 512);
      ln_res<<<CM / 4, 256, 0, stream>>>(
          x_b + R * 512, s_kq, g1 + l * 512, be1 + l * 512, x_b + R * 512);
      // FFN (inner-chunked to keep s_t small)
      for (int mc = 0; mc < CM; mc += MI) {
        gemm_bt<1, 0><<<dim3(16, MI / 128), 256, 0, stream>>>(
            x_b + (R + mc) * 512, w1T + (size_t)l * 512 * 2048, b1 + l * 2048,
            s_t, MI, 2048, 512);
        gemm_bt<0, 0><<<dim3(4, MI / 128), 256, 0, stream>>>(
            s_t, w2T + (size_t)l * 2048 * 512, b2 + l * 512,
            s_vT + (size_t)mc * 512, MI, 512, 2048);
      }
      ln_res<<<CM / 4, 256, 0, stream>>>(
          x_b + R * 512, s_vT, g2 + l * 512, be2 + l * 512, x_b + R * 512);
    }
  }

  // head per chunk: concat -> fc1(relu) -> fc2(relu) -> logits (fp32 to d_out)
  for (int cc = 0; cc < NC; ++cc) {
    const size_t R = (size_t)cc * CM;
    concat2_k<<<CM / 4, 256, 0, stream>>>(x_b + R * 512, qd + R, qemb, s_kq);
    gemm_bt<1, 0><<<dim3(4, CM / 128), 256, 0, stream>>>(
        s_kq, wo1T, bo1, s_o, CM, 512, 1024);
    gemm_bt<1, 0><<<dim3(2, CM / 128), 256, 0, stream>>>(
        s_o, wo2T, bo2, s_t, CM, 256, 512);
    gemm_bt<0, 1><<<dim3(3, CM / 128), 256, 0, stream>>>(
        s_t, wo3T, bo3, out + R * 300, CM, 300, 256);
  }
}